// Round 6
// baseline (484.643 us; speedup 1.0000x reference)
//
#include <hip/hip_runtime.h>
#include <hip/hip_bf16.h>
#include <stdint.h>

#define IN_F   4096
#define OUT_F  4096
#define MROWS  8192   // 4 * 2048
#define NT     64     // K-tiles of BK=64

typedef __bf16 bf16x8 __attribute__((ext_vector_type(8)));
typedef float  f32x4  __attribute__((ext_vector_type(4)));
typedef unsigned short ushort8v __attribute__((ext_vector_type(8)));

__device__ __constant__ float NF4_TAB[16] = {
    -1.0f, -0.6961928009986877f, -0.5250730514526367f, -0.39491748809814453f,
    -0.28444138169288635f, -0.18477343022823334f, -0.09105003625154495f, 0.0f,
    0.07958029955625534f, 0.16093020141124725f, 0.24611230194568634f, 0.33791524171829224f,
    0.44070982933044434f, 0.5626170039176941f, 0.7229568362236023f, 1.0f,
};

__device__ __forceinline__ unsigned short f2bf_rne(float f) {
    unsigned u = __builtin_bit_cast(unsigned, f);
    return (unsigned short)((u + 0x7FFFu + ((u >> 16) & 1u)) >> 16);
}

// ---------------------------------------------------------------------------
// Fused prep: blocks [0,512) dequant NF4 -> bf16 W; blocks [512,2048) f32->bf16 X
// ---------------------------------------------------------------------------
__global__ __launch_bounds__(256) void prep_kernel(
        const float* __restrict__ x, const int* __restrict__ packed,
        const float* __restrict__ absmax,
        unsigned short* __restrict__ Wb, unsigned short* __restrict__ Xb) {
    __shared__ float tab[16];
    if (threadIdx.x < 16) tab[threadIdx.x] = NF4_TAB[threadIdx.x];
    __syncthreads();

    const int bid = blockIdx.x;
    if (bid < 512) {
        const int ngroups = OUT_F * IN_F / 8;   // 2,097,152
        const int stride = 512 * 256;
        for (int g = bid * 256 + threadIdx.x; g < ngroups; g += stride) {
            int4 pv = reinterpret_cast<const int4*>(packed)[g];
            float am = absmax[g >> 3];
            ushort8v o;
            o[0] = f2bf_rne(tab[(pv.x >> 4) & 0xF] * am);
            o[1] = f2bf_rne(tab[ pv.x       & 0xF] * am);
            o[2] = f2bf_rne(tab[(pv.y >> 4) & 0xF] * am);
            o[3] = f2bf_rne(tab[ pv.y       & 0xF] * am);
            o[4] = f2bf_rne(tab[(pv.z >> 4) & 0xF] * am);
            o[5] = f2bf_rne(tab[ pv.z       & 0xF] * am);
            o[6] = f2bf_rne(tab[(pv.w >> 4) & 0xF] * am);
            o[7] = f2bf_rne(tab[ pv.w       & 0xF] * am);
            *reinterpret_cast<ushort8v*>(&Wb[(size_t)g * 8]) = o;
        }
    } else {
        const int ngroups = MROWS * IN_F / 8;   // 4,194,304
        const int stride = 1536 * 256;
        for (int g = (bid - 512) * 256 + threadIdx.x; g < ngroups; g += stride) {
            float4 v0 = reinterpret_cast<const float4*>(x)[2 * g];
            float4 v1 = reinterpret_cast<const float4*>(x)[2 * g + 1];
            ushort8v o;
            o[0] = f2bf_rne(v0.x); o[1] = f2bf_rne(v0.y);
            o[2] = f2bf_rne(v0.z); o[3] = f2bf_rne(v0.w);
            o[4] = f2bf_rne(v1.x); o[5] = f2bf_rne(v1.y);
            o[6] = f2bf_rne(v1.z); o[7] = f2bf_rne(v1.w);
            *reinterpret_cast<ushort8v*>(&Xb[(size_t)g * 8]) = o;
        }
    }
}

// ---------------------------------------------------------------------------
// 256x256 bf16 GEMM, 2 phases per K-tile (BK=64), C = A*B^T + bias.
// 512 threads = 8 waves (2Mx4N), per-wave out 128x64.
// Phase = {12 ds_read_b128 (B + A-mq0 + A-mq1 of one K-half); 2 stage-calls;
//          32 MFMA; VMW(6); BAR}. Barriers: 2 per K-tile (was 8).
// Stage schedule (steady, tile t, buf b=t&1):
//   phA stages A(t+1,1),B(t+1,1) -> buf(1-b).kh1, last read t-1.phB (1 BAR back)
//   phB stages A(t+2,0),B(t+2,0) -> buf(b).kh0,   last read t.phA   (1 BAR back)
// VMW(6) every phase-end: induction shows each phase drains the 4 oldest
// gloads = exactly the regions consumed next phase; depth stays ~2.5 phases,
// never drains to 0 mid-loop. WAR-safe: a wave's ds_reads are lgkm-consumed
// (compiler wait before MFMA) before it reaches its closing BAR, so stages
// issued post-BAR by any wave can't overwrite live reads.
// Swizzle (involution): byte X = L ^ (((L>>7)&7)<<4); linear gload dest +
// inverse-permuted global source + XOR'd ds_read (rule #21). Conflicts = 0.
// ---------------------------------------------------------------------------
#define GLOAD16(gp, lp)                                                        \
    __builtin_amdgcn_global_load_lds(                                          \
        (const __attribute__((address_space(1))) void*)(gp),                   \
        (__attribute__((address_space(3))) void*)(lp), 16, 0, 0)

#define BARF()  asm volatile("s_barrier" ::: "memory")
#define VMW(n)  asm volatile("s_waitcnt vmcnt(" #n ")" ::: "memory")

__global__ __launch_bounds__(512) void gemm256_kernel(
        const unsigned short* __restrict__ A,   // [MROWS][IN_F] bf16
        const unsigned short* __restrict__ B,   // [OUT_F][IN_F] bf16
        const float* __restrict__ bias,
        float* __restrict__ C) {                // [MROWS][OUT_F] f32
    __shared__ __align__(16) unsigned short lds[65536];   // 128 KiB

    const int tid  = threadIdx.x;
    const int lane = tid & 63;
    const int wave = tid >> 6;
    const int wr   = wave >> 2;   // 0..1
    const int wcn  = wave & 3;    // 0..3
    const int lr   = lane & 15;
    const int lg   = lane >> 4;

    // T1: bijective XCD swizzle, 512 wgs = 8 XCDs x 64
    const int bid = blockIdx.x;
    const int wg  = (bid & 7) * 64 + (bid >> 3);
    const int bm  = (wg >> 4) << 8;   // 32 M-tiles
    const int bn  = (wg & 15) << 8;   // 16 N-tiles

    // staging source mapping (inverse swizzle on global addr)
    int srow[2], skel[2];
#pragma unroll
    for (int r = 0; r < 2; ++r) {
        int c = tid + r * 512;
        int L = c * 16;
        int sw = L ^ (((L >> 7) & 7) << 4);
        srow[r] = sw >> 6;
        skel[r] = (sw & 63) >> 1;
    }
    const unsigned short* pA0 = A + (size_t)(bm + srow[0]) * IN_F + skel[0];
    const unsigned short* pA1 = A + (size_t)(bm + srow[1]) * IN_F + skel[1];
    const unsigned short* pB0 = B + (size_t)(bn + srow[0]) * IN_F + skel[0];
    const unsigned short* pB1 = B + (size_t)(bn + srow[1]) * IN_F + skel[1];
    const int d0 = tid * 8, d1 = tid * 8 + 4096;

#define STAGE_A(t, kh) do {                                                    \
        int _b = ((t) & 1) * 32768 + (kh) * 8192;                              \
        int _k = (t) * 64 + (kh) * 32;                                         \
        GLOAD16(pA0 + _k, &lds[_b + d0]);                                      \
        GLOAD16(pA1 + _k, &lds[_b + d1]); } while (0)
#define STAGE_B(t, kh) do {                                                    \
        int _b = ((t) & 1) * 32768 + 16384 + (kh) * 8192;                      \
        int _k = (t) * 64 + (kh) * 32;                                         \
        GLOAD16(pB0 + _k, &lds[_b + d0]);                                      \
        GLOAD16(pB1 + _k, &lds[_b + d1]); } while (0)

    const int laneoff = ((lr * 64 + lg * 16) ^ (((lr >> 1) & 7) << 4)) >> 1;
    const int arow = wr * 128;
    const int brow = wcn * 64;

    f32x4  acc[8][4] = {};
    bf16x8 af0[4], af1[4], bfv[4];

#define LOADB(b, kh) do {                                                      \
        int _base = (b) * 32768 + 16384 + (kh) * 8192 + brow * 32 + laneoff;   \
        bfv[0] = *reinterpret_cast<const bf16x8*>(&lds[_base]);                \
        bfv[1] = *reinterpret_cast<const bf16x8*>(&lds[_base + 512]);          \
        bfv[2] = *reinterpret_cast<const bf16x8*>(&lds[_base + 1024]);         \
        bfv[3] = *reinterpret_cast<const bf16x8*>(&lds[_base + 1536]); } while (0)
#define LOADA(b, kh, mq, dst) do {                                             \
        int _base = (b) * 32768 + (kh) * 8192 + (arow + (mq) * 64) * 32 + laneoff; \
        dst[0] = *reinterpret_cast<const bf16x8*>(&lds[_base]);                \
        dst[1] = *reinterpret_cast<const bf16x8*>(&lds[_base + 512]);          \
        dst[2] = *reinterpret_cast<const bf16x8*>(&lds[_base + 1024]);         \
        dst[3] = *reinterpret_cast<const bf16x8*>(&lds[_base + 1536]); } while (0)

    // 32 MFMAs: mq0 (acc[0..3]) then mq1 (acc[4..7]), one setprio bracket
#define MFMA32() do {                                                          \
        __builtin_amdgcn_s_setprio(1);                                         \
        _Pragma("unroll")                                                      \
        for (int mi = 0; mi < 4; ++mi)                                         \
            _Pragma("unroll")                                                  \
            for (int ni = 0; ni < 4; ++ni)                                     \
                acc[mi][ni] = __builtin_amdgcn_mfma_f32_16x16x32_bf16(         \
                    af0[mi], bfv[ni], acc[mi][ni], 0, 0, 0);                   \
        _Pragma("unroll")                                                      \
        for (int mi = 0; mi < 4; ++mi)                                         \
            _Pragma("unroll")                                                  \
            for (int ni = 0; ni < 4; ++ni)                                     \
                acc[4 + mi][ni] = __builtin_amdgcn_mfma_f32_16x16x32_bf16(     \
                    af1[mi], bfv[ni], acc[4 + mi][ni], 0, 0, 0);               \
        __builtin_amdgcn_s_setprio(0); } while (0)

    // phase: reads (kh) -> stages -> MFMA32 -> VMW -> BAR
#define PHASE(b, kh, S1, S2, V) do {                                           \
        LOADB(b, kh); LOADA(b, kh, 0, af0); LOADA(b, kh, 1, af1);              \
        S1; S2; MFMA32(); V; BARF(); } while (0)

    // prologue: issue 12 gloads in consumption order; VMW(6) drains tile0.kh0
    // and A(0,1); outstanding = {B(0,1), A(1,0), B(1,0)} = steady invariant.
    STAGE_A(0, 0); STAGE_B(0, 0); STAGE_A(0, 1);
    STAGE_B(0, 1); STAGE_A(1, 0); STAGE_B(1, 0);
    VMW(6);
    BARF();

    // steady state: t in [0, 62)
#pragma unroll 2
    for (int t = 0; t < NT - 2; ++t) {
        const int b = t & 1;
        PHASE(b, 0, STAGE_A(t + 1, 1), STAGE_B(t + 1, 1), VMW(6));
        PHASE(b, 1, STAGE_A(t + 2, 0), STAGE_B(t + 2, 0), VMW(6));
    }
    // tile 62 (b=0): phA stages tile63.kh1; phB: no stage, drain B(63,0)
    PHASE(0, 0, STAGE_A(63, 1), STAGE_B(63, 1), VMW(6));
    PHASE(0, 1, , , VMW(4));
    // tile 63 (b=1): phA drains A(63,1),B(63,1); phB pure compute
    PHASE(1, 0, , , VMW(0));
    PHASE(1, 1, , , );

    // epilogue: C/D layout col = lane&15, row = (lane>>4)*4 + j
#pragma unroll
    for (int a = 0; a < 8; ++a) {
        const int row0 = bm + wr * 128 + (a >> 2) * 64 + (a & 3) * 16 + lg * 4;
#pragma unroll
        for (int ni = 0; ni < 4; ++ni) {
            const int col = bn + wcn * 64 + ni * 16 + lr;
            const float bs = bias[col];
            float* cp = C + (size_t)row0 * OUT_F + col;
#pragma unroll
            for (int j = 0; j < 4; ++j)
                cp[(size_t)j * OUT_F] = acc[a][ni][j] + bs;
        }
    }
}

// ---------------------------------------------------------------------------
extern "C" void kernel_launch(void* const* d_in, const int* in_sizes, int n_in,
                              void* d_out, int out_size, void* d_ws, size_t ws_size,
                              hipStream_t stream) {
    const float* x      = (const float*)d_in[0];
    const int*   packed = (const int*)d_in[1];
    const float* absmax = (const float*)d_in[2];
    const float* bias   = (const float*)d_in[3];
    float* out = (float*)d_out;

    unsigned short* Wb = (unsigned short*)d_ws;                  // 32 MiB
    unsigned short* Xb = Wb + (size_t)OUT_F * IN_F;              // 64 MiB

    prep_kernel<<<2048, 256, 0, stream>>>(x, packed, absmax, Wb, Xb);
    gemm256_kernel<<<512, 512, 0, stream>>>(Xb, Wb, bias, out);
}